// Round 15
// baseline (245.504 us; speedup 1.0000x reference)
//
#include <hip/hip_runtime.h>
#include <hip/hip_bf16.h>

#define BATCH 16
#define SEQ   2048
#define HD    128
#define QB    64
#define KB    64
#define NT    (SEQ/QB)   // 32 q-tiles per batch

#define WSTR 136   // LDS row stride (shorts) for Wk/Wv/Qh/Kh tiles
#define VSTR 72    // LDS row stride (shorts) for V^T / P

typedef __attribute__((ext_vector_type(8))) short bf16x8;
typedef __attribute__((ext_vector_type(4))) float f32x4;

#define MFMA(a,b,c) __builtin_amdgcn_mfma_f32_16x16x32_bf16(a,b,c,0,0,0)

__device__ __forceinline__ short f2bf(float f){
  union{float f; unsigned u;} v; v.f = f;
  unsigned r = (v.u + 0x7FFFu + ((v.u>>16)&1u))>>16;
  return (short)r;
}
__device__ __forceinline__ float bf2f(short s){
  union{unsigned u; float f;} v; v.u = ((unsigned)(unsigned short)s)<<16; return v.f;
}
__device__ __forceinline__ bf16x8 pack8(f32x4 a, f32x4 b){
  bf16x8 r;
  r[0]=f2bf(a[0]); r[1]=f2bf(a[1]); r[2]=f2bf(a[2]); r[3]=f2bf(a[3]);
  r[4]=f2bf(b[0]); r[5]=f2bf(b[1]); r[6]=f2bf(b[2]); r[7]=f2bf(b[3]);
  return r;
}
__device__ __forceinline__ bf16x8 ldfrag(const float* base, size_t eo){
  const float* p = base + eo;
  return pack8(*(const f32x4*)p, *(const f32x4*)(p+4));
}

// ---------------- fused QKV-projection + causal flash attention -------------
// One block = (batch b, pair pr): q-tiles pr and 31-pr (balanced causal work).
// 4 waves x 64 lanes. LDS 120 KB. fp32 inputs (verified on device via mask
// probe R3==R4), fp32 OUTPUT (R14 probe: harness decodes d_out as float32).
// Machinery bit-equal to the fp32 arbiter (R4==R5). Wiring: documented dict
// order (no surviving evidence against it after the output-dtype correction).
__global__ __launch_bounds__(256, 1)
void attn_fused(const float* __restrict__ qin, const float* __restrict__ kin,
                const float* __restrict__ vin,
                const float* __restrict__ Wq, const float* __restrict__ bq,
                const float* __restrict__ Wk, const float* __restrict__ bk,
                const float* __restrict__ Wv, const float* __restrict__ bv,
                float* __restrict__ out)
{
  __shared__ __align__(16) short WkL[HD*WSTR];   // Wk [h][e] bf16
  __shared__ __align__(16) short WvL[HD*WSTR];   // Wv [h][e] bf16
  __shared__ __align__(16) short KhL[KB*WSTR];
  __shared__ __align__(16) short VtL[HD*VSTR];
  __shared__ __align__(16) short QPL[QB*WSTR];   // Qh staging / per-wave P

  const int b  = blockIdx.y;
  const int pr = blockIdx.x;
  const size_t boff = (size_t)b*SEQ*HD;
  float* Ob = out + boff;

  const int tid = threadIdx.x;
  const int w = tid>>6, l = tid&63, li = l&15, g = l>>4;
  short* Pw = QPL + w*(16*VSTR);
  const float sc = 0.088388347648318447f;        // 1/sqrt(128)

  // ---- stage Wk, Wv into LDS as bf16 ([h][e], torch (H,E) storage)
  #pragma unroll
  for (int it=0; it<8; it++){
    int c = tid + it*256;
    int row = c>>4, c8 = c&15;
    *(bf16x8*)&WkL[row*WSTR + c8*8] = ldfrag(Wk, (size_t)row*HD + c8*8);
    *(bf16x8*)&WvL[row*WSTR + c8*8] = ldfrag(Wv, (size_t)row*HD + c8*8);
  }
  float bbk[8], bbv[8];
  #pragma unroll
  for (int ct=0; ct<8; ct++){
    bbk[ct] = bk[ct*16+li];
    bbv[ct] = bv[ct*16+li];
  }
  __syncthreads();

  for (int half=0; half<2; half++){
    const int qt = (half==0) ? pr : (NT-1-pr);
    const int qrow0 = qt*QB;

    { // Qh tile -> QPL
      bf16x8 qA[4];
      #pragma unroll
      for (int ks=0; ks<4; ks++)
        qA[ks] = ldfrag(qin, boff + (size_t)(qrow0 + w*16 + li)*HD + ks*32 + g*8);
      #pragma unroll
      for (int ct=0; ct<8; ct++){
        f32x4 acc = (f32x4){0.f,0.f,0.f,0.f};
        #pragma unroll
        for (int ks=0; ks<4; ks++){
          bf16x8 bf = ldfrag(Wq, (size_t)(ct*16+li)*HD + ks*32 + g*8);
          acc = MFMA(qA[ks], bf, acc);
        }
        float bias = bq[ct*16+li];
        #pragma unroll
        for (int r=0; r<4; r++)
          QPL[(w*16+g*4+r)*WSTR + ct*16+li] = f2bf(acc[r] + bias);
      }
    }
    __syncthreads();

    bf16x8 qfr[4];
    #pragma unroll
    for (int ks=0; ks<4; ks++)
      qfr[ks] = *(const bf16x8*)&QPL[(w*16+li)*WSTR + ks*32 + g*8];

    f32x4 oacc[8];
    #pragma unroll
    for (int dt=0; dt<8; dt++) oacc[dt] = (f32x4){0.f,0.f,0.f,0.f};
    float mrow[4] = {-1e30f,-1e30f,-1e30f,-1e30f};
    float lsum[4] = {0.f,0.f,0.f,0.f};

    const int nkv = qt + 1;
    for (int kt=0; kt<nkv; kt++){
      __syncthreads();

      { // Kh tile = k_in @ Wk^T + bk
        bf16x8 kA[4];
        #pragma unroll
        for (int ks=0; ks<4; ks++)
          kA[ks] = ldfrag(kin, boff + (size_t)(kt*KB + w*16 + li)*HD + ks*32 + g*8);
        #pragma unroll
        for (int ct=0; ct<8; ct++){
          f32x4 acc = (f32x4){0.f,0.f,0.f,0.f};
          #pragma unroll
          for (int ks=0; ks<4; ks++){
            bf16x8 bf = *(const bf16x8*)&WkL[(ct*16+li)*WSTR + ks*32 + g*8];
            acc = MFMA(kA[ks], bf, acc);
          }
          #pragma unroll
          for (int r=0; r<4; r++)
            KhL[(w*16+g*4+r)*WSTR + ct*16+li] = f2bf(acc[r] + bbk[ct]);
        }
      }
      { // Vh tile -> transposed in LDS
        bf16x8 vA[4];
        #pragma unroll
        for (int ks=0; ks<4; ks++)
          vA[ks] = ldfrag(vin, boff + (size_t)(kt*KB + w*16 + li)*HD + ks*32 + g*8);
        #pragma unroll
        for (int ct=0; ct<8; ct++){
          f32x4 acc = (f32x4){0.f,0.f,0.f,0.f};
          #pragma unroll
          for (int ks=0; ks<4; ks++){
            bf16x8 bf = *(const bf16x8*)&WvL[(ct*16+li)*WSTR + ks*32 + g*8];
            acc = MFMA(vA[ks], bf, acc);
          }
          #pragma unroll
          for (int r=0; r<4; r++)
            VtL[(ct*16+li)*VSTR + w*16+g*4+r] = f2bf(acc[r] + bbv[ct]);
        }
      }
      __syncthreads();

      // ---- QK^T : S[q=g*4+r][k=ct*16+li] in s[ct][r]
      f32x4 s[4];
      #pragma unroll
      for (int ct=0; ct<4; ct++) s[ct] = (f32x4){0.f,0.f,0.f,0.f};
      #pragma unroll
      for (int ct=0; ct<4; ct++){
        #pragma unroll
        for (int ks=0; ks<4; ks++){
          bf16x8 kfr = *(const bf16x8*)&KhL[(ct*16+li)*WSTR + ks*32 + g*8];
          s[ct] = MFMA(qfr[ks], kfr, s[ct]);
        }
      }

      // ---- online softmax
      float sv[4][4];
      float pm[4] = {-1e30f,-1e30f,-1e30f,-1e30f};
      const bool diag = (kt == qt);
      #pragma unroll
      for (int ct=0; ct<4; ct++){
        #pragma unroll
        for (int r=0; r<4; r++){
          float x = s[ct][r]*sc;
          if (diag && (ct*16+li) > (w*16 + g*4 + r)) x = -1e30f;
          sv[ct][r] = x;
          pm[r] = fmaxf(pm[r], x);
        }
      }
      #pragma unroll
      for (int msk=1; msk<16; msk<<=1){
        #pragma unroll
        for (int r=0; r<4; r++) pm[r] = fmaxf(pm[r], __shfl_xor(pm[r], msk));
      }
      float scl[4], ps[4];
      #pragma unroll
      for (int r=0; r<4; r++){
        float mn = fmaxf(mrow[r], pm[r]);
        scl[r] = __expf(mrow[r]-mn);
        mrow[r] = mn;
        ps[r] = 0.f;
      }
      #pragma unroll
      for (int ct=0; ct<4; ct++){
        #pragma unroll
        for (int r=0; r<4; r++){
          float p = __expf(sv[ct][r]-mrow[r]);
          sv[ct][r] = p;
          ps[r] += p;
        }
      }
      #pragma unroll
      for (int msk=1; msk<16; msk<<=1){
        #pragma unroll
        for (int r=0; r<4; r++) ps[r] += __shfl_xor(ps[r], msk);
      }
      #pragma unroll
      for (int r=0; r<4; r++) lsum[r] = lsum[r]*scl[r] + ps[r];
      #pragma unroll
      for (int dt=0; dt<8; dt++){
        #pragma unroll
        for (int r=0; r<4; r++) oacc[dt][r] *= scl[r];
      }

      // ---- P -> per-wave LDS (transpose to A-frag layout)
      #pragma unroll
      for (int ct=0; ct<4; ct++){
        #pragma unroll
        for (int r=0; r<4; r++)
          Pw[(g*4+r)*VSTR + ct*16 + li] = f2bf(sv[ct][r]);
      }

      // ---- PV
      #pragma unroll
      for (int ks2=0; ks2<2; ks2++){
        bf16x8 afr = *(const bf16x8*)&Pw[li*VSTR + ks2*32 + g*8];
        #pragma unroll
        for (int dt=0; dt<8; dt++){
          bf16x8 bfr = *(const bf16x8*)&VtL[(dt*16+li)*VSTR + ks2*32 + g*8];
          oacc[dt] = MFMA(afr, bfr, oacc[dt]);
        }
      }
    } // kt

    // ---- epilogue: fp32 stores (harness reads d_out as float32)
    #pragma unroll
    for (int dt=0; dt<8; dt++){
      #pragma unroll
      for (int r=0; r<4; r++){
        float o = oacc[dt][r] / lsum[r];
        Ob[(size_t)(qrow0 + w*16 + g*4 + r)*HD + dt*16 + li] = o;
      }
    }
    __syncthreads();
  } // half
}

// ---------------- launch: documented dict order ------------------------------
// d_in = [q, k, v, Wq, bq, Wk, bk, Wv, bv, mask]; mask applied structurally.
extern "C" void kernel_launch(void* const* d_in, const int* in_sizes, int n_in,
                              void* d_out, int out_size, void* d_ws, size_t ws_size,
                              hipStream_t stream)
{
  dim3 ag(NT/2, BATCH);
  attn_fused<<<ag, 256, 0, stream>>>(
      (const float*)d_in[0],   // q
      (const float*)d_in[1],   // k
      (const float*)d_in[2],   // v
      (const float*)d_in[3],   // Wq
      (const float*)d_in[4],   // bq
      (const float*)d_in[5],   // Wk
      (const float*)d_in[6],   // bk
      (const float*)d_in[7],   // Wv
      (const float*)d_in[8],   // bv
      (float*)d_out);
}

// Round 16
// 143.464 us; speedup vs baseline: 1.7113x; 1.7113x over previous
//
#include <hip/hip_runtime.h>
#include <hip/hip_bf16.h>

#define BATCH 16
#define SEQ   2048
#define HD    128
#define TB    64            // tile rows (q and kv)
#define NT    (SEQ/TB)      // 32 tiles per batch

typedef __attribute__((ext_vector_type(8))) short bf16x8;
typedef __attribute__((ext_vector_type(4))) float f32x4;

#define MFMA(a,b,c) __builtin_amdgcn_mfma_f32_16x16x32_bf16(a,b,c,0,0,0)

__device__ __forceinline__ short f2bf(float f){
  union{float f; unsigned u;} v; v.f = f;
  unsigned r = (v.u + 0x7FFFu + ((v.u>>16)&1u))>>16;
  return (short)r;
}
__device__ __forceinline__ bf16x8 pack8(f32x4 a, f32x4 b){
  bf16x8 r;
  r[0]=f2bf(a[0]); r[1]=f2bf(a[1]); r[2]=f2bf(a[2]); r[3]=f2bf(a[3]);
  r[4]=f2bf(b[0]); r[5]=f2bf(b[1]); r[6]=f2bf(b[2]); r[7]=f2bf(b[3]);
  return r;
}
__device__ __forceinline__ bf16x8 ldfrag(const float* base, size_t eo){
  const float* p = base + eo;
  return pack8(*(const f32x4*)p, *(const f32x4*)(p+4));
}

// ---------------- kernel 1: projections -> ws (bf16) -------------------------
// z=0: Qh row-major [B*S][128]; z=1: Kh row-major; z=2: Vh TRANSPOSED
// [B][128][2048] so the PV B-fragment is a contiguous 16B load.
__global__ __launch_bounds__(256)
void proj_kernel(const float* __restrict__ q, const float* __restrict__ k,
                 const float* __restrict__ v,
                 const float* __restrict__ Wq, const float* __restrict__ bq,
                 const float* __restrict__ Wk, const float* __restrict__ bk,
                 const float* __restrict__ Wv, const float* __restrict__ bv,
                 short* __restrict__ ws)
{
  __shared__ __align__(16) short VT[HD*72];        // transpose bounce (z==2)

  const int z = blockIdx.y;
  const float* x  = z==0 ? q  : (z==1 ? k  : v);
  const float* W  = z==0 ? Wq : (z==1 ? Wk : Wv);
  const float* bb = z==0 ? bq : (z==1 ? bk : bv);

  const int tid = threadIdx.x;
  const int w = tid>>6, l = tid&63, li = l&15, g = l>>4;
  const int rowbase = blockIdx.x*TB + w*16;        // global row in B*S

  bf16x8 afr[4];
  const float* xr = x + (size_t)(rowbase+li)*HD + g*8;
  #pragma unroll
  for (int ks=0; ks<4; ks++) afr[ks] = ldfrag(xr, (size_t)ks*32);

  f32x4 acc[8];
  #pragma unroll
  for (int ct=0; ct<8; ct++) acc[ct] = (f32x4){0.f,0.f,0.f,0.f};
  #pragma unroll
  for (int ct=0; ct<8; ct++){
    #pragma unroll
    for (int ks=0; ks<4; ks++){
      bf16x8 bfr = ldfrag(W, (size_t)(ct*16+li)*HD + ks*32 + g*8);
      acc[ct] = MFMA(afr[ks], bfr, acc[ct]);
    }
  }

  if (z < 2){
    short* y = ws + (size_t)z*BATCH*SEQ*HD;
    #pragma unroll
    for (int ct=0; ct<8; ct++){
      float bias = bb[ct*16+li];
      #pragma unroll
      for (int r=0; r<4; r++)
        y[(size_t)(rowbase + g*4 + r)*HD + ct*16+li] = f2bf(acc[ct][r] + bias);
    }
  } else {
    #pragma unroll
    for (int ct=0; ct<8; ct++){
      float bias = bb[ct*16+li];
      #pragma unroll
      for (int r=0; r<4; r++)
        VT[(ct*16+li)*72 + w*16+g*4+r] = f2bf(acc[ct][r] + bias);
    }
    __syncthreads();
    const int bx = blockIdx.x;                     // 0..511
    const int b = bx>>5, s0 = (bx&31)*TB;
    short* vt = ws + (size_t)2*BATCH*SEQ*HD + (size_t)b*HD*SEQ;
    const int d = tid>>1, half = tid&1;            // 128 rows x 2 halves
    short* dst = vt + (size_t)d*SEQ + s0 + half*32;
    const short* src = &VT[d*72 + half*32];
    #pragma unroll
    for (int j=0; j<4; j++) *(bf16x8*)(dst + j*8) = *(const bf16x8*)(src + j*8);
  }
}

// ---------------- kernel 2: causal flash attention (bf16 ws in, fp32 out) ----
// One block per (qt, b): 4 waves x 16 q-rows. K/V tiles staged in XOR-swizzled
// unpadded LDS (chunk ^= row&7 on 16B chunks -> conflict-free ds_read_b128).
__global__ __launch_bounds__(256, 2)
void attn_kernel(const short* __restrict__ ws, float* __restrict__ out)
{
  __shared__ __align__(16) short KL[TB*HD];        // 16 KB, swizzled [64][128]
  __shared__ __align__(16) short VL[HD*TB];        // 16 KB, swizzled [128][64]
  __shared__ __align__(16) short PL[4][16*72];     // per-wave P, padded

  const int b  = blockIdx.y;
  const int qt = (NT-1) - blockIdx.x;              // big tiles dispatch first
  const int tid = threadIdx.x;
  const int w = tid>>6, l = tid&63, li = l&15, g = l>>4;

  const short* Qw = ws;
  const short* Kw = ws + (size_t)BATCH*SEQ*HD;
  const short* Vt = ws + (size_t)2*BATCH*SEQ*HD;

  const int qrow0 = qt*TB;
  const size_t qbase = (size_t)b*SEQ + qrow0;
  short* Pw = &PL[w][0];
  const float sc = 0.088388347648318447f;          // 1/sqrt(128)

  bf16x8 qfr[4];
  #pragma unroll
  for (int ks=0; ks<4; ks++)
    qfr[ks] = *(const bf16x8*)&Qw[(qbase + w*16 + li)*HD + ks*32 + g*8];

  f32x4 oacc[8];
  #pragma unroll
  for (int dt=0; dt<8; dt++) oacc[dt] = (f32x4){0.f,0.f,0.f,0.f};
  float mrow[4] = {-1e30f,-1e30f,-1e30f,-1e30f};
  float lsum[4] = {0.f,0.f,0.f,0.f};

  for (int kt=0; kt<=qt; kt++){
    __syncthreads();                               // previous readers done
    #pragma unroll
    for (int it=0; it<4; it++){                    // K: 1024 chunks of 16B
      int c = tid + it*256;
      int row = c>>4, c8 = c&15;
      *(bf16x8*)&KL[row*HD + ((c8 ^ (row&7)))*8] =
        *(const bf16x8*)&Kw[((size_t)b*SEQ + kt*TB + row)*HD + c8*8];
    }
    #pragma unroll
    for (int it=0; it<4; it++){                    // V^T: 1024 chunks of 16B
      int c = tid + it*256;
      int row = c>>3, c8 = c&7;                    // row = d (0..127)
      *(bf16x8*)&VL[row*TB + ((c8 ^ (row&7)))*8] =
        *(const bf16x8*)&Vt[((size_t)b*HD + row)*SEQ + kt*TB + c8*8];
    }
    __syncthreads();

    // ---- QK^T : S[q=g*4+r][k=ct*16+li] in s[ct][r]
    f32x4 s[4];
    #pragma unroll
    for (int ct=0; ct<4; ct++) s[ct] = (f32x4){0.f,0.f,0.f,0.f};
    #pragma unroll
    for (int ct=0; ct<4; ct++){
      const int row = ct*16 + li;
      #pragma unroll
      for (int ks=0; ks<4; ks++){
        const int chunk = ks*4 + g;
        bf16x8 kfr = *(const bf16x8*)&KL[row*HD + ((chunk ^ (row&7)))*8];
        s[ct] = MFMA(qfr[ks], kfr, s[ct]);
      }
    }

    // ---- online softmax
    float sv[4][4];
    float pm[4] = {-1e30f,-1e30f,-1e30f,-1e30f};
    const bool diag = (kt == qt);
    #pragma unroll
    for (int ct=0; ct<4; ct++){
      #pragma unroll
      for (int r=0; r<4; r++){
        float x = s[ct][r]*sc;
        if (diag && (ct*16+li) > (w*16 + g*4 + r)) x = -1e30f;
        sv[ct][r] = x;
        pm[r] = fmaxf(pm[r], x);
      }
    }
    #pragma unroll
    for (int msk=1; msk<16; msk<<=1){
      #pragma unroll
      for (int r=0; r<4; r++) pm[r] = fmaxf(pm[r], __shfl_xor(pm[r], msk));
    }
    float scl[4], ps[4];
    #pragma unroll
    for (int r=0; r<4; r++){
      float mn = fmaxf(mrow[r], pm[r]);
      scl[r] = __expf(mrow[r]-mn);
      mrow[r] = mn;
      ps[r] = 0.f;
    }
    #pragma unroll
    for (int ct=0; ct<4; ct++){
      #pragma unroll
      for (int r=0; r<4; r++){
        float p = __expf(sv[ct][r]-mrow[r]);
        sv[ct][r] = p;
        ps[r] += p;
      }
    }
    #pragma unroll
    for (int msk=1; msk<16; msk<<=1){
      #pragma unroll
      for (int r=0; r<4; r++) ps[r] += __shfl_xor(ps[r], msk);
    }
    #pragma unroll
    for (int r=0; r<4; r++) lsum[r] = lsum[r]*scl[r] + ps[r];
    #pragma unroll
    for (int dt=0; dt<8; dt++){
      #pragma unroll
      for (int r=0; r<4; r++) oacc[dt][r] *= scl[r];
    }

    // ---- P -> per-wave LDS (transpose to A-frag layout)
    #pragma unroll
    for (int ct=0; ct<4; ct++){
      #pragma unroll
      for (int r=0; r<4; r++)
        Pw[(g*4+r)*72 + ct*16 + li] = f2bf(sv[ct][r]);
    }

    // ---- PV : O[q][dt*16+li] += P[q][k] * Vh[k][d]
    #pragma unroll
    for (int ks2=0; ks2<2; ks2++){
      bf16x8 afr = *(const bf16x8*)&Pw[li*72 + ks2*32 + g*8];
      #pragma unroll
      for (int dt=0; dt<8; dt++){
        const int row = dt*16 + li;
        const int chunk = ks2*4 + g;
        bf16x8 bfr = *(const bf16x8*)&VL[row*TB + ((chunk ^ (row&7)))*8];
        oacc[dt] = MFMA(afr, bfr, oacc[dt]);
      }
    }
  } // kt

  // ---- epilogue: fp32 out
  float* Ob = out + qbase*HD;
  #pragma unroll
  for (int dt=0; dt<8; dt++){
    #pragma unroll
    for (int r=0; r<4; r++){
      Ob[(size_t)(w*16 + g*4 + r)*HD + dt*16 + li] = oacc[dt][r] / lsum[r];
    }
  }
}

// ---------------- launch -----------------------------------------------------
// d_in = [q, k, v, Wq, bq, Wk, bk, Wv, bv, mask] (documented dict order,
// confirmed R15). ws: Qh | Kh | Vh^T, bf16, 25.2 MB total.
extern "C" void kernel_launch(void* const* d_in, const int* in_sizes, int n_in,
                              void* d_out, int out_size, void* d_ws, size_t ws_size,
                              hipStream_t stream)
{
  short* ws = (short*)d_ws;

  dim3 pg(BATCH*SEQ/TB, 3);
  proj_kernel<<<pg, 256, 0, stream>>>(
      (const float*)d_in[0], (const float*)d_in[1], (const float*)d_in[2],
      (const float*)d_in[3], (const float*)d_in[4],
      (const float*)d_in[5], (const float*)d_in[6],
      (const float*)d_in[7], (const float*)d_in[8], ws);

  dim3 ag(NT, BATCH);
  attn_kernel<<<ag, 256, 0, stream>>>(ws, (float*)d_out);
}

// Round 17
// 135.429 us; speedup vs baseline: 1.8128x; 1.0593x over previous
//
#include <hip/hip_runtime.h>
#include <hip/hip_bf16.h>

#define BATCH 16
#define SEQ   2048
#define HD    128
#define TB    64            // tile rows (q and kv)
#define NT    (SEQ/TB)      // 32 tiles per batch
#define PLANE ((size_t)BATCH*SEQ*HD)   // shorts per ws plane

typedef __attribute__((ext_vector_type(8))) short bf16x8;
typedef __attribute__((ext_vector_type(4))) float f32x4;

#define MFMA(a,b,c) __builtin_amdgcn_mfma_f32_16x16x32_bf16(a,b,c,0,0,0)

__device__ __forceinline__ short f2bf(float f){
  union{float f; unsigned u;} v; v.f = f;
  unsigned r = (v.u + 0x7FFFu + ((v.u>>16)&1u))>>16;
  return (short)r;
}
__device__ __forceinline__ bf16x8 pack8(f32x4 a, f32x4 b){
  bf16x8 r;
  r[0]=f2bf(a[0]); r[1]=f2bf(a[1]); r[2]=f2bf(a[2]); r[3]=f2bf(a[3]);
  r[4]=f2bf(b[0]); r[5]=f2bf(b[1]); r[6]=f2bf(b[2]); r[7]=f2bf(b[3]);
  return r;
}
__device__ __forceinline__ bf16x8 ldfrag(const float* base, size_t eo){
  const float* p = base + eo;
  return pack8(*(const f32x4*)p, *(const f32x4*)(p+4));
}

// ---------------- kernel 1: projections -> ws (bf16) -------------------------
// z=0: Qh row-major [B*S][128].
// z=1: Kh as per-tile 16KB LDS IMAGES (swizzle baked in): chunk(row,c8) at
//      row*16 + (c8 ^ (row&7)), row=0..63 (s), c8=0..15 (d/8).
// z=2: Vh^T as per-tile 16KB images: chunk(d,c8) at d*8 + (c8 ^ (d&7)),
//      d=0..127, c8=0..7 (s/8).
// All global stores are 16B vector chunks via LDS bounce (coalesced).
__global__ __launch_bounds__(256)
void proj_kernel(const float* __restrict__ q, const float* __restrict__ k,
                 const float* __restrict__ v,
                 const float* __restrict__ Wq, const float* __restrict__ bq,
                 const float* __restrict__ Wk, const float* __restrict__ bk,
                 const float* __restrict__ Wv, const float* __restrict__ bv,
                 short* __restrict__ ws)
{
  __shared__ __align__(16) short T[TB*136];    // [s_local][h] bounce (z<2)
  __shared__ __align__(16) short VT[HD*72];    // [h][s_local] bounce (z==2)

  const int z = blockIdx.y;
  const float* x  = z==0 ? q  : (z==1 ? k  : v);
  const float* W  = z==0 ? Wq : (z==1 ? Wk : Wv);
  const float* bb = z==0 ? bq : (z==1 ? bk : bv);

  const int tid = threadIdx.x;
  const int w = tid>>6, l = tid&63, li = l&15, g = l>>4;
  const int bx = blockIdx.x;                   // tile id 0..511 (b = bx>>5)
  const int rowbase = bx*TB + w*16;

  bf16x8 afr[4];
  const float* xr = x + (size_t)(rowbase+li)*HD + g*8;
  #pragma unroll
  for (int ks=0; ks<4; ks++) afr[ks] = ldfrag(xr, (size_t)ks*32);

  f32x4 acc[8];
  #pragma unroll
  for (int ct=0; ct<8; ct++) acc[ct] = (f32x4){0.f,0.f,0.f,0.f};
  #pragma unroll
  for (int ct=0; ct<8; ct++){
    #pragma unroll
    for (int ks=0; ks<4; ks++){
      bf16x8 bfr = ldfrag(W, (size_t)(ct*16+li)*HD + ks*32 + g*8);
      acc[ct] = MFMA(afr[ks], bfr, acc[ct]);
    }
  }

  if (z < 2){
    #pragma unroll
    for (int ct=0; ct<8; ct++){
      float bias = bb[ct*16+li];
      #pragma unroll
      for (int r=0; r<4; r++)
        T[(w*16+g*4+r)*136 + ct*16+li] = f2bf(acc[ct][r] + bias);
    }
    __syncthreads();
    if (z == 0){
      short* dst = ws + (size_t)bx*TB*HD;
      #pragma unroll
      for (int it=0; it<4; it++){
        int c = tid + it*256, row = c>>4, c8 = c&15;
        *(bf16x8*)(dst + row*HD + c8*8) = *(const bf16x8*)&T[row*136 + c8*8];
      }
    } else {
      short* dst = ws + PLANE + (size_t)bx*8192;
      #pragma unroll
      for (int it=0; it<4; it++){
        int c = tid + it*256, row = c>>4, c8 = c&15;
        int chunk = row*16 + (c8 ^ (row&7));
        *(bf16x8*)(dst + chunk*8) = *(const bf16x8*)&T[row*136 + c8*8];
      }
    }
  } else {
    #pragma unroll
    for (int ct=0; ct<8; ct++){
      float bias = bb[ct*16+li];
      #pragma unroll
      for (int r=0; r<4; r++)
        VT[(ct*16+li)*72 + w*16+g*4+r] = f2bf(acc[ct][r] + bias);
    }
    __syncthreads();
    short* dst = ws + 2*PLANE + (size_t)bx*8192;
    const int d = tid>>1, hf = tid&1;
    #pragma unroll
    for (int j=0; j<4; j++){
      int c8 = hf*4 + j;
      int chunk = d*8 + (c8 ^ (d&7));
      *(bf16x8*)(dst + chunk*8) = *(const bf16x8*)&VT[d*72 + c8*8];
    }
  }
}

// ---------------- kernel 2: causal flash attention ---------------------------
// T14 async-split + LDS double-buffer: issue tile kt+1 global loads -> compute
// tile kt -> ds_write kt+1 -> ONE barrier. Tile images make staging linear.
__global__ __launch_bounds__(256, 2)
void attn_kernel(const short* __restrict__ ws, float* __restrict__ out)
{
  __shared__ __align__(16) short KVL[2][16384];  // [buf][K 8192 | V 8192], 64KB
  __shared__ __align__(16) short PL[4][16*72];   // per-wave P, padded

  // XCD-bijective mapping: 512 blocks = 8 XCD x 64; 2 batches per XCD.
  const int bid = blockIdx.x;
  const int xcd = bid & 7, slot = bid >> 3;
  const int b   = xcd*2 + (slot >> 5);
  const int qt  = 31 - (slot & 31);              // big tiles first

  const int tid = threadIdx.x;
  const int w = tid>>6, l = tid&63, li = l&15, g = l>>4;

  const short* Qw   = ws;
  const short* KimgB = ws + PLANE   + (size_t)b*NT*8192;
  const short* VimgB = ws + 2*PLANE + (size_t)b*NT*8192;

  const size_t qbase = (size_t)b*SEQ + qt*TB;
  short* Pw = &PL[w][0];
  const float sc = 0.088388347648318447f;        // 1/sqrt(128)

  bf16x8 qfr[4];
  #pragma unroll
  for (int ks=0; ks<4; ks++)
    qfr[ks] = *(const bf16x8*)&Qw[(qbase + w*16 + li)*HD + ks*32 + g*8];

  f32x4 oacc[8];
  #pragma unroll
  for (int dt=0; dt<8; dt++) oacc[dt] = (f32x4){0.f,0.f,0.f,0.f};
  float mrow[4] = {-1e30f,-1e30f,-1e30f,-1e30f};
  float lsum[4] = {0.f,0.f,0.f,0.f};

  bf16x8 stg[8];
  #define LOADT(kt_) do{                                              \
    const short* sK = KimgB + (size_t)(kt_)*8192;                     \
    const short* sV = VimgB + (size_t)(kt_)*8192;                     \
    _Pragma("unroll")                                                 \
    for (int j=0;j<4;j++) stg[j]   = *(const bf16x8*)(sK + (tid + j*256)*8); \
    _Pragma("unroll")                                                 \
    for (int j=0;j<4;j++) stg[4+j] = *(const bf16x8*)(sV + (tid + j*256)*8); \
  }while(0)
  #define WRT(nb_) do{                                                \
    short* dK = &KVL[nb_][0];                                         \
    short* dV = &KVL[nb_][8192];                                      \
    _Pragma("unroll")                                                 \
    for (int j=0;j<4;j++) *(bf16x8*)(dK + (tid+j*256)*8) = stg[j];    \
    _Pragma("unroll")                                                 \
    for (int j=0;j<4;j++) *(bf16x8*)(dV + (tid+j*256)*8) = stg[4+j];  \
  }while(0)

  LOADT(0); WRT(0); __syncthreads();
  int cur = 0;

  for (int kt=0; kt<=qt; kt++){
    const bool pre = (kt < qt);
    if (pre) LOADT(kt+1);                        // global latency hides under compute

    const short* KL = &KVL[cur][0];
    const short* VL = &KVL[cur][8192];

    // ---- QK^T : S[q=g*4+r][k=ct*16+li] in s[ct][r]
    f32x4 s[4];
    #pragma unroll
    for (int ct=0; ct<4; ct++) s[ct] = (f32x4){0.f,0.f,0.f,0.f};
    #pragma unroll
    for (int ct=0; ct<4; ct++){
      const int row = ct*16 + li;
      #pragma unroll
      for (int ks=0; ks<4; ks++){
        const int chunk = ks*4 + g;
        bf16x8 kfr = *(const bf16x8*)&KL[row*HD + ((chunk ^ (row&7)))*8];
        s[ct] = MFMA(qfr[ks], kfr, s[ct]);
      }
    }

    // ---- online softmax
    float sv[4][4];
    float pm[4] = {-1e30f,-1e30f,-1e30f,-1e30f};
    const bool diag = (kt == qt);
    #pragma unroll
    for (int ct=0; ct<4; ct++){
      #pragma unroll
      for (int r=0; r<4; r++){
        float x = s[ct][r]*sc;
        if (diag && (ct*16+li) > (w*16 + g*4 + r)) x = -1e30f;
        sv[ct][r] = x;
        pm[r] = fmaxf(pm[r], x);
      }
    }
    #pragma unroll
    for (int msk=1; msk<16; msk<<=1){
      #pragma unroll
      for (int r=0; r<4; r++) pm[r] = fmaxf(pm[r], __shfl_xor(pm[r], msk));
    }
    float scl[4], ps[4];
    #pragma unroll
    for (int r=0; r<4; r++){
      float mn = fmaxf(mrow[r], pm[r]);
      scl[r] = __expf(mrow[r]-mn);
      mrow[r] = mn;
      ps[r] = 0.f;
    }
    #pragma unroll
    for (int ct=0; ct<4; ct++){
      #pragma unroll
      for (int r=0; r<4; r++){
        float p = __expf(sv[ct][r]-mrow[r]);
        sv[ct][r] = p;
        ps[r] += p;
      }
    }
    #pragma unroll
    for (int msk=1; msk<16; msk<<=1){
      #pragma unroll
      for (int r=0; r<4; r++) ps[r] += __shfl_xor(ps[r], msk);
    }
    #pragma unroll
    for (int r=0; r<4; r++) lsum[r] = lsum[r]*scl[r] + ps[r];
    #pragma unroll
    for (int dt=0; dt<8; dt++){
      #pragma unroll
      for (int r=0; r<4; r++) oacc[dt][r] *= scl[r];
    }

    // ---- P -> per-wave LDS
    #pragma unroll
    for (int ct=0; ct<4; ct++){
      #pragma unroll
      for (int r=0; r<4; r++)
        Pw[(g*4+r)*72 + ct*16 + li] = f2bf(sv[ct][r]);
    }

    // ---- PV
    #pragma unroll
    for (int ks2=0; ks2<2; ks2++){
      bf16x8 afr = *(const bf16x8*)&Pw[li*72 + ks2*32 + g*8];
      #pragma unroll
      for (int dt=0; dt<8; dt++){
        const int row = dt*16 + li;
        const int chunk = ks2*4 + g;
        bf16x8 bfr = *(const bf16x8*)&VL[row*TB + ((chunk ^ (row&7)))*8];
        oacc[dt] = MFMA(afr, bfr, oacc[dt]);
      }
    }

    if (pre) WRT(cur^1);                         // safe: other waves read buf[cur]
    __syncthreads();                             // single barrier per iteration
    cur ^= 1;
  } // kt

  // ---- epilogue: fp32 out
  float* Ob = out + qbase*HD;
  #pragma unroll
  for (int dt=0; dt<8; dt++){
    #pragma unroll
    for (int r=0; r<4; r++){
      Ob[(size_t)(w*16 + g*4 + r)*HD + dt*16 + li] = oacc[dt][r] / lsum[r];
    }
  }
  #undef LOADT
  #undef WRT
}

// ---------------- launch -----------------------------------------------------
// d_in = [q, k, v, Wq, bq, Wk, bk, Wv, bv, mask] (confirmed R15).
// ws: Qh | Kimg | Vimg (bf16, 24 MB).
extern "C" void kernel_launch(void* const* d_in, const int* in_sizes, int n_in,
                              void* d_out, int out_size, void* d_ws, size_t ws_size,
                              hipStream_t stream)
{
  short* ws = (short*)d_ws;

  dim3 pg(BATCH*SEQ/TB, 3);
  proj_kernel<<<pg, 256, 0, stream>>>(
      (const float*)d_in[0], (const float*)d_in[1], (const float*)d_in[2],
      (const float*)d_in[3], (const float*)d_in[4],
      (const float*)d_in[5], (const float*)d_in[6],
      (const float*)d_in[7], (const float*)d_in[8], ws);

  attn_kernel<<<dim3(BATCH*NT), 256, 0, stream>>>(ws, (float*)d_out);
}

// Round 18
// 123.404 us; speedup vs baseline: 1.9894x; 1.0974x over previous
//
#include <hip/hip_runtime.h>
#include <hip/hip_bf16.h>

#define BATCH 16
#define SEQ   2048
#define HD    128
#define TB    64            // tile rows (q and kv)
#define NT    (SEQ/TB)      // 32 tiles per batch
#define PLANE ((size_t)BATCH*SEQ*HD)   // shorts per ws plane

typedef __attribute__((ext_vector_type(8))) short bf16x8;
typedef __attribute__((ext_vector_type(4))) float f32x4;

#define MFMA(a,b,c) __builtin_amdgcn_mfma_f32_16x16x32_bf16(a,b,c,0,0,0)

__device__ __forceinline__ short f2bf(float f){
  union{float f; unsigned u;} v; v.f = f;
  unsigned r = (v.u + 0x7FFFu + ((v.u>>16)&1u))>>16;
  return (short)r;
}
__device__ __forceinline__ bf16x8 pack8(f32x4 a, f32x4 b){
  bf16x8 r;
  r[0]=f2bf(a[0]); r[1]=f2bf(a[1]); r[2]=f2bf(a[2]); r[3]=f2bf(a[3]);
  r[4]=f2bf(b[0]); r[5]=f2bf(b[1]); r[6]=f2bf(b[2]); r[7]=f2bf(b[3]);
  return r;
}
__device__ __forceinline__ bf16x8 ldfrag(const float* base, size_t eo){
  const float* p = base + eo;
  return pack8(*(const f32x4*)p, *(const f32x4*)(p+4));
}

// ---------------- kernel 0: W fp32 -> bf16 once ------------------------------
__global__ __launch_bounds__(256)
void wconv_kernel(const float* __restrict__ Wq, const float* __restrict__ Wk,
                  const float* __restrict__ Wv, short* __restrict__ wb)
{
  int i = (blockIdx.x*256 + threadIdx.x)*8;        // 0..49144, covers 3*16384
  const float* src = (i < 16384) ? Wq : (i < 32768 ? Wk : Wv);
  int off = i & 16383;
  f32x4 a = *(const f32x4*)(src + off);
  f32x4 b = *(const f32x4*)(src + off + 4);
  *(bf16x8*)(wb + i) = pack8(a, b);
}

// ---------------- kernel 1: projections -> ws (bf16) -------------------------
// z=0: Qh row-major [B*S][128].
// z=1: Kh per-tile 16KB images (swizzle baked): chunk(row,c8)=row*16+(c8^(row&7))
// z=2: Vh^T per-tile images: chunk(d,c8)=d*8+(c8^(d&7))
__global__ __launch_bounds__(256)
void proj_kernel(const float* __restrict__ q, const float* __restrict__ k,
                 const float* __restrict__ v,
                 const float* __restrict__ bq, const float* __restrict__ bk,
                 const float* __restrict__ bv,
                 const short* __restrict__ wb, short* __restrict__ ws)
{
  __shared__ __align__(16) short T[TB*136];    // [s_local][h] bounce (z<2)
  __shared__ __align__(16) short VT[HD*72];    // [h][s_local] bounce (z==2)

  const int z = blockIdx.y;
  const float* x  = z==0 ? q  : (z==1 ? k  : v);
  const float* bb = z==0 ? bq : (z==1 ? bk : bv);
  const short* W  = wb + (size_t)z*HD*HD;      // bf16 weights

  const int tid = threadIdx.x;
  const int w = tid>>6, l = tid&63, li = l&15, g = l>>4;
  const int bx = blockIdx.x;                   // tile id 0..511 (b = bx>>5)
  const int rowbase = bx*TB + w*16;

  bf16x8 afr[4];
  const float* xr = x + (size_t)(rowbase+li)*HD + g*8;
  #pragma unroll
  for (int ks=0; ks<4; ks++) afr[ks] = ldfrag(xr, (size_t)ks*32);

  f32x4 acc[8];
  #pragma unroll
  for (int ct=0; ct<8; ct++) acc[ct] = (f32x4){0.f,0.f,0.f,0.f};
  #pragma unroll
  for (int ct=0; ct<8; ct++){
    #pragma unroll
    for (int ks=0; ks<4; ks++){
      bf16x8 bfr = *(const bf16x8*)(W + (size_t)(ct*16+li)*HD + ks*32 + g*8);
      acc[ct] = MFMA(afr[ks], bfr, acc[ct]);
    }
  }

  if (z < 2){
    #pragma unroll
    for (int ct=0; ct<8; ct++){
      float bias = bb[ct*16+li];
      #pragma unroll
      for (int r=0; r<4; r++)
        T[(w*16+g*4+r)*136 + ct*16+li] = f2bf(acc[ct][r] + bias);
    }
    __syncthreads();
    if (z == 0){
      short* dst = ws + (size_t)bx*TB*HD;
      #pragma unroll
      for (int it=0; it<4; it++){
        int c = tid + it*256, row = c>>4, c8 = c&15;
        *(bf16x8*)(dst + row*HD + c8*8) = *(const bf16x8*)&T[row*136 + c8*8];
      }
    } else {
      short* dst = ws + PLANE + (size_t)bx*8192;
      #pragma unroll
      for (int it=0; it<4; it++){
        int c = tid + it*256, row = c>>4, c8 = c&15;
        int chunk = row*16 + (c8 ^ (row&7));
        *(bf16x8*)(dst + chunk*8) = *(const bf16x8*)&T[row*136 + c8*8];
      }
    }
  } else {
    #pragma unroll
    for (int ct=0; ct<8; ct++){
      float bias = bb[ct*16+li];
      #pragma unroll
      for (int r=0; r<4; r++)
        VT[(ct*16+li)*72 + w*16+g*4+r] = f2bf(acc[ct][r] + bias);
    }
    __syncthreads();
    short* dst = ws + 2*PLANE + (size_t)bx*8192;
    const int d = tid>>1, hf = tid&1;
    #pragma unroll
    for (int j=0; j<4; j++){
      int c8 = hf*4 + j;
      int chunk = d*8 + (c8 ^ (d&7));
      *(bf16x8*)(dst + chunk*8) = *(const bf16x8*)&VT[d*72 + c8*8];
    }
  }
}

// ---------------- kernel 2: causal flash attention ---------------------------
// T14 async-split + LDS double-buffer, one barrier/iter. Load-balanced qt map:
// round-robin CU placement gives CU_i slots i and i+32 -> qt (31-i) and i,
// i.e. ~33 KV-iterations per CU instead of 2..64.
__global__ __launch_bounds__(256, 2)
void attn_kernel(const short* __restrict__ ws, float* __restrict__ out)
{
  __shared__ __align__(16) short KVL[2][16384];  // [buf][K 8192 | V 8192], 64KB
  __shared__ __align__(16) short PL[4][16*72];   // per-wave P, padded

  const int bid = blockIdx.x;
  const int xcd = bid & 7, slot = bid >> 3;
  const int b   = xcd*2 + (slot >> 5);
  const int sl  = slot & 31;
  const int qt  = (sl < 16) ? (31 - sl) : (sl - 16);   // pair big+small per CU

  const int tid = threadIdx.x;
  const int w = tid>>6, l = tid&63, li = l&15, g = l>>4;

  const short* Qw    = ws;
  const short* KimgB = ws + PLANE   + (size_t)b*NT*8192;
  const short* VimgB = ws + 2*PLANE + (size_t)b*NT*8192;

  const size_t qbase = (size_t)b*SEQ + qt*TB;
  short* Pw = &PL[w][0];
  const float sc = 0.088388347648318447f;        // 1/sqrt(128)

  bf16x8 qfr[4];
  #pragma unroll
  for (int ks=0; ks<4; ks++)
    qfr[ks] = *(const bf16x8*)&Qw[(qbase + w*16 + li)*HD + ks*32 + g*8];

  f32x4 oacc[8];
  #pragma unroll
  for (int dt=0; dt<8; dt++) oacc[dt] = (f32x4){0.f,0.f,0.f,0.f};
  float mrow[4] = {-1e30f,-1e30f,-1e30f,-1e30f};
  float lsum[4] = {0.f,0.f,0.f,0.f};

  bf16x8 stg[8];
  #define LOADT(kt_) do{                                              \
    const short* sK = KimgB + (size_t)(kt_)*8192;                     \
    const short* sV = VimgB + (size_t)(kt_)*8192;                     \
    _Pragma("unroll")                                                 \
    for (int j=0;j<4;j++) stg[j]   = *(const bf16x8*)(sK + (tid + j*256)*8); \
    _Pragma("unroll")                                                 \
    for (int j=0;j<4;j++) stg[4+j] = *(const bf16x8*)(sV + (tid + j*256)*8); \
  }while(0)
  #define WRT(nb_) do{                                                \
    short* dK = &KVL[nb_][0];                                         \
    short* dV = &KVL[nb_][8192];                                      \
    _Pragma("unroll")                                                 \
    for (int j=0;j<4;j++) *(bf16x8*)(dK + (tid+j*256)*8) = stg[j];    \
    _Pragma("unroll")                                                 \
    for (int j=0;j<4;j++) *(bf16x8*)(dV + (tid+j*256)*8) = stg[4+j];  \
  }while(0)

  LOADT(0); WRT(0); __syncthreads();
  int cur = 0;

  for (int kt=0; kt<=qt; kt++){
    const bool pre = (kt < qt);
    if (pre) LOADT(kt+1);

    const short* KL = &KVL[cur][0];
    const short* VL = &KVL[cur][8192];

    // ---- QK^T : S[q=g*4+r][k=ct*16+li] in s[ct][r]
    f32x4 s[4];
    #pragma unroll
    for (int ct=0; ct<4; ct++) s[ct] = (f32x4){0.f,0.f,0.f,0.f};
    #pragma unroll
    for (int ct=0; ct<4; ct++){
      const int row = ct*16 + li;
      #pragma unroll
      for (int ks=0; ks<4; ks++){
        const int chunk = ks*4 + g;
        bf16x8 kfr = *(const bf16x8*)&KL[row*HD + ((chunk ^ (row&7)))*8];
        s[ct] = MFMA(qfr[ks], kfr, s[ct]);
      }
    }

    // ---- online softmax
    float sv[4][4];
    float pm[4] = {-1e30f,-1e30f,-1e30f,-1e30f};
    const bool diag = (kt == qt);
    #pragma unroll
    for (int ct=0; ct<4; ct++){
      #pragma unroll
      for (int r=0; r<4; r++){
        float x = s[ct][r]*sc;
        if (diag && (ct*16+li) > (w*16 + g*4 + r)) x = -1e30f;
        sv[ct][r] = x;
        pm[r] = fmaxf(pm[r], x);
      }
    }
    #pragma unroll
    for (int msk=1; msk<16; msk<<=1){
      #pragma unroll
      for (int r=0; r<4; r++) pm[r] = fmaxf(pm[r], __shfl_xor(pm[r], msk));
    }
    float scl[4], ps[4];
    #pragma unroll
    for (int r=0; r<4; r++){
      float mn = fmaxf(mrow[r], pm[r]);
      scl[r] = __expf(mrow[r]-mn);
      mrow[r] = mn;
      ps[r] = 0.f;
    }
    #pragma unroll
    for (int ct=0; ct<4; ct++){
      #pragma unroll
      for (int r=0; r<4; r++){
        float p = __expf(sv[ct][r]-mrow[r]);
        sv[ct][r] = p;
        ps[r] += p;
      }
    }
    #pragma unroll
    for (int msk=1; msk<16; msk<<=1){
      #pragma unroll
      for (int r=0; r<4; r++) ps[r] += __shfl_xor(ps[r], msk);
    }
    #pragma unroll
    for (int r=0; r<4; r++) lsum[r] = lsum[r]*scl[r] + ps[r];
    #pragma unroll
    for (int dt=0; dt<8; dt++){
      #pragma unroll
      for (int r=0; r<4; r++) oacc[dt][r] *= scl[r];
    }

    // ---- P -> per-wave LDS
    #pragma unroll
    for (int ct=0; ct<4; ct++){
      #pragma unroll
      for (int r=0; r<4; r++)
        Pw[(g*4+r)*72 + ct*16 + li] = f2bf(sv[ct][r]);
    }

    // ---- PV
    #pragma unroll
    for (int ks2=0; ks2<2; ks2++){
      bf16x8 afr = *(const bf16x8*)&Pw[li*72 + ks2*32 + g*8];
      #pragma unroll
      for (int dt=0; dt<8; dt++){
        const int row = dt*16 + li;
        const int chunk = ks2*4 + g;
        bf16x8 bfr = *(const bf16x8*)&VL[row*TB + ((chunk ^ (row&7)))*8];
        oacc[dt] = MFMA(afr, bfr, oacc[dt]);
      }
    }

    if (pre) WRT(cur^1);
    __syncthreads();
    cur ^= 1;
  } // kt

  // ---- epilogue: fp32 out
  float* Ob = out + qbase*HD;
  #pragma unroll
  for (int dt=0; dt<8; dt++){
    #pragma unroll
    for (int r=0; r<4; r++){
      Ob[(size_t)(w*16 + g*4 + r)*HD + dt*16 + li] = oacc[dt][r] / lsum[r];
    }
  }
  #undef LOADT
  #undef WRT
}

// ---------------- launch -----------------------------------------------------
// d_in = [q, k, v, Wq, bq, Wk, bk, Wv, bv, mask] (confirmed R15).
// ws: Qh | Kimg | Vimg | Wbf16 (25.3 MB).
extern "C" void kernel_launch(void* const* d_in, const int* in_sizes, int n_in,
                              void* d_out, int out_size, void* d_ws, size_t ws_size,
                              hipStream_t stream)
{
  short* ws = (short*)d_ws;
  short* wb = ws + 3*PLANE;

  wconv_kernel<<<24, 256, 0, stream>>>(
      (const float*)d_in[3], (const float*)d_in[5], (const float*)d_in[7], wb);

  dim3 pg(BATCH*SEQ/TB, 3);
  proj_kernel<<<pg, 256, 0, stream>>>(
      (const float*)d_in[0], (const float*)d_in[1], (const float*)d_in[2],
      (const float*)d_in[4], (const float*)d_in[6], (const float*)d_in[8],
      wb, ws);

  attn_kernel<<<dim3(BATCH*NT), 256, 0, stream>>>(ws, (float*)d_out);
}

// Round 20
// 114.621 us; speedup vs baseline: 2.1419x; 1.0766x over previous
//
#include <hip/hip_runtime.h>
#include <hip/hip_bf16.h>

#define BATCH 16
#define SEQ   2048
#define HD    128
#define TB    64            // proj tile rows
#define QB2   128           // attn q-tile rows
#define KB2   128           // attn kv-tile rows
#define NTB   (SEQ/KB2)     // 16 kv tiles per batch
#define PLANE ((size_t)BATCH*SEQ*HD)   // shorts per ws plane

typedef __attribute__((ext_vector_type(8))) short bf16x8;
typedef __attribute__((ext_vector_type(4))) float f32x4;

#define MFMA(a,b,c) __builtin_amdgcn_mfma_f32_16x16x32_bf16(a,b,c,0,0,0)

__device__ __forceinline__ short f2bf(float f){
  union{float f; unsigned u;} v; v.f = f;
  unsigned r = (v.u + 0x7FFFu + ((v.u>>16)&1u))>>16;
  return (short)r;
}
__device__ __forceinline__ bf16x8 pack8(f32x4 a, f32x4 b){
  bf16x8 r;
  r[0]=f2bf(a[0]); r[1]=f2bf(a[1]); r[2]=f2bf(a[2]); r[3]=f2bf(a[3]);
  r[4]=f2bf(b[0]); r[5]=f2bf(b[1]); r[6]=f2bf(b[2]); r[7]=f2bf(b[3]);
  return r;
}
__device__ __forceinline__ bf16x8 ldfrag(const float* base, size_t eo){
  const float* p = base + eo;
  return pack8(*(const f32x4*)p, *(const f32x4*)(p+4));
}

// ---------------- kernel 0: W fp32 -> bf16 once ------------------------------
__global__ __launch_bounds__(256)
void wconv_kernel(const float* __restrict__ Wq, const float* __restrict__ Wk,
                  const float* __restrict__ Wv, short* __restrict__ wb)
{
  int i = (blockIdx.x*256 + threadIdx.x)*8;
  const float* src = (i < 16384) ? Wq : (i < 32768 ? Wk : Wv);
  int off = i & 16383;
  f32x4 a = *(const f32x4*)(src + off);
  f32x4 b = *(const f32x4*)(src + off + 4);
  *(bf16x8*)(wb + i) = pack8(a, b);
}

// ---------------- kernel 1: projections -> ws (bf16) -------------------------
// z=0: Qh row-major. z=1: Kh 32KB images [128 rows]: chunk(r,c8)=r*16+(c8^(r&7)).
// z=2: Vh^T 32KB images [d][c8g 0..15]: chunk(d,c8g)=d*16+(c8g^(d&7)).
__global__ __launch_bounds__(256)
void proj_kernel(const float* __restrict__ q, const float* __restrict__ k,
                 const float* __restrict__ v,
                 const float* __restrict__ bq, const float* __restrict__ bk,
                 const float* __restrict__ bv,
                 const short* __restrict__ wb, short* __restrict__ ws)
{
  __shared__ __align__(16) short T[TB*136];    // [s_local][h] bounce (z<2)
  __shared__ __align__(16) short VT[HD*72];    // [h][s_local] bounce (z==2)

  const int z = blockIdx.y;
  const float* x  = z==0 ? q  : (z==1 ? k  : v);
  const float* bb = z==0 ? bq : (z==1 ? bk : bv);
  const short* W  = wb + (size_t)z*HD*HD;

  const int tid = threadIdx.x;
  const int w = tid>>6, l = tid&63, li = l&15, g = l>>4;
  const int bx = blockIdx.x;                   // 64-row tile id (b = bx>>5)
  const int rowbase = bx*TB + w*16;

  bf16x8 afr[4];
  const float* xr = x + (size_t)(rowbase+li)*HD + g*8;
  #pragma unroll
  for (int ks=0; ks<4; ks++) afr[ks] = ldfrag(xr, (size_t)ks*32);

  f32x4 acc[8];
  #pragma unroll
  for (int ct=0; ct<8; ct++) acc[ct] = (f32x4){0.f,0.f,0.f,0.f};
  #pragma unroll
  for (int ct=0; ct<8; ct++){
    #pragma unroll
    for (int ks=0; ks<4; ks++){
      bf16x8 bfr = *(const bf16x8*)(W + (size_t)(ct*16+li)*HD + ks*32 + g*8);
      acc[ct] = MFMA(afr[ks], bfr, acc[ct]);
    }
  }

  const int img  = (bx>>1);                    // 128-row image id
  const int half = bx & 1;                     // which 64-row half

  if (z < 2){
    #pragma unroll
    for (int ct=0; ct<8; ct++){
      float bias = bb[ct*16+li];
      #pragma unroll
      for (int r=0; r<4; r++)
        T[(w*16+g*4+r)*136 + ct*16+li] = f2bf(acc[ct][r] + bias);
    }
    __syncthreads();
    if (z == 0){
      short* dst = ws + (size_t)bx*TB*HD;
      #pragma unroll
      for (int it=0; it<4; it++){
        int c = tid + it*256, row = c>>4, c8 = c&15;
        *(bf16x8*)(dst + row*HD + c8*8) = *(const bf16x8*)&T[row*136 + c8*8];
      }
    } else {
      short* dst = ws + PLANE + (size_t)img*16384;
      #pragma unroll
      for (int it=0; it<4; it++){
        int c = tid + it*256, row = c>>4, c8 = c&15;
        int r128 = half*64 + row;
        int chunk = r128*16 + (c8 ^ (r128&7));
        *(bf16x8*)(dst + chunk*8) = *(const bf16x8*)&T[row*136 + c8*8];
      }
    }
  } else {
    #pragma unroll
    for (int ct=0; ct<8; ct++){
      float bias = bb[ct*16+li];
      #pragma unroll
      for (int r=0; r<4; r++)
        VT[(ct*16+li)*72 + w*16+g*4+r] = f2bf(acc[ct][r] + bias);
    }
    __syncthreads();
    short* dst = ws + 2*PLANE + (size_t)img*16384;
    const int d = tid>>1, hf = tid&1;
    #pragma unroll
    for (int j=0; j<4; j++){
      int c8l = hf*4 + j;
      int c8g = half*8 + c8l;
      int chunk = d*16 + (c8g ^ (d&7));
      *(bf16x8*)(dst + chunk*8) = *(const bf16x8*)&VT[d*72 + c8l*8];
    }
  }
}

// ---------------- kernel 2: causal flash attention ---------------------------
// 8 waves x 128-row q-tile, 128-row kv-tiles: critical path 16 iterations.
// K/V double-buffered (128KB) + per-wave P (18.4KB); 1 barrier/iteration.
// R19 bug fixed: 4 staging chunks/thread (512 x 4 x 16B = 32KB = tile size);
// 8 chunks overflowed into the other buffer's K region -> cross-wave race.
__global__ __launch_bounds__(512, 2)
void attn_kernel(const short* __restrict__ ws, float* __restrict__ out)
{
  __shared__ __align__(16) short KVL[2][32768]; // [buf][K 16384 | V 16384]
  __shared__ __align__(16) short PL[8][16*72];  // per-wave P, padded

  const int bid  = blockIdx.x;                  // 256 blocks
  const int xcd  = bid & 7, slot = bid >> 3;
  const int b    = xcd*2 + (slot >> 4);
  const int qt   = slot & 15;

  const int tid = threadIdx.x;
  const int w = tid>>6, l = tid&63, li = l&15, g = l>>4;

  const short* Qw    = ws;
  const short* KimgB = ws + PLANE   + (size_t)b*NTB*16384;
  const short* VimgB = ws + 2*PLANE + (size_t)b*NTB*16384;

  const size_t qbase = (size_t)b*SEQ + qt*QB2;
  short* Pw = &PL[w][0];
  const float sc = 0.088388347648318447f;       // 1/sqrt(128)

  bf16x8 qfr[4];
  #pragma unroll
  for (int ks=0; ks<4; ks++)
    qfr[ks] = *(const bf16x8*)&Qw[(qbase + w*16 + li)*HD + ks*32 + g*8];

  f32x4 oacc[8];
  #pragma unroll
  for (int dt=0; dt<8; dt++) oacc[dt] = (f32x4){0.f,0.f,0.f,0.f};
  float mrow[4] = {-1e30f,-1e30f,-1e30f,-1e30f};
  float lsum[4] = {0.f,0.f,0.f,0.f};

  bf16x8 stg[8];
  #define LOADT(kt_) do{                                                    \
    const short* sK = KimgB + (size_t)(kt_)*16384;                          \
    const short* sV = VimgB + (size_t)(kt_)*16384;                          \
    _Pragma("unroll")                                                       \
    for (int j=0;j<4;j++) stg[j]   = *(const bf16x8*)(sK + (tid + j*512)*8);\
    _Pragma("unroll")                                                       \
    for (int j=0;j<4;j++) stg[4+j] = *(const bf16x8*)(sV + (tid + j*512)*8);\
  }while(0)
  #define WRT(nb_) do{                                                     \
    short* dK = &KVL[nb_][0];                                              \
    short* dV = &KVL[nb_][16384];                                          \
    _Pragma("unroll")                                                      \
    for (int j=0;j<4;j++) *(bf16x8*)(dK + (tid+j*512)*8) = stg[j];         \
    _Pragma("unroll")                                                      \
    for (int j=0;j<4;j++) *(bf16x8*)(dV + (tid+j*512)*8) = stg[4+j];       \
  }while(0)

  LOADT(0); WRT(0); __syncthreads();
  int cur = 0;

  for (int kt=0; kt<=qt; kt++){
    const bool pre = (kt < qt);
    if (pre) LOADT(kt+1);

    const short* KL = &KVL[cur][0];
    const short* VL = &KVL[cur][16384];

    // ---- QK^T : S[q=g*4+r][k=ct*16+li], ct 0..7 (128 k)
    f32x4 s[8];
    #pragma unroll
    for (int ct=0; ct<8; ct++) s[ct] = (f32x4){0.f,0.f,0.f,0.f};
    #pragma unroll
    for (int ct=0; ct<8; ct++){
      const int row = ct*16 + li;
      #pragma unroll
      for (int ks=0; ks<4; ks++){
        const int chunk = row*16 + ((ks*4 + g) ^ (row&7));
        bf16x8 kfr = *(const bf16x8*)&KL[chunk*8];
        s[ct] = MFMA(qfr[ks], kfr, s[ct]);
      }
    }

    // ---- online softmax
    float sv[8][4];
    float pm[4] = {-1e30f,-1e30f,-1e30f,-1e30f};
    const bool diag = (kt == qt);
    #pragma unroll
    for (int ct=0; ct<8; ct++){
      #pragma unroll
      for (int r=0; r<4; r++){
        float x = s[ct][r]*sc;
        if (diag && (ct*16+li) > (w*16 + g*4 + r)) x = -1e30f;
        sv[ct][r] = x;
        pm[r] = fmaxf(pm[r], x);
      }
    }
    #pragma unroll
    for (int msk=1; msk<16; msk<<=1){
      #pragma unroll
      for (int r=0; r<4; r++) pm[r] = fmaxf(pm[r], __shfl_xor(pm[r], msk));
    }
    float scl[4], ps[4];
    #pragma unroll
    for (int r=0; r<4; r++){
      float mn = fmaxf(mrow[r], pm[r]);
      scl[r] = __expf(mrow[r]-mn);
      mrow[r] = mn;
      ps[r] = 0.f;
    }
    #pragma unroll
    for (int ct=0; ct<8; ct++){
      #pragma unroll
      for (int r=0; r<4; r++){
        float p = __expf(sv[ct][r]-mrow[r]);
        sv[ct][r] = p;
        ps[r] += p;
      }
    }
    #pragma unroll
    for (int msk=1; msk<16; msk<<=1){
      #pragma unroll
      for (int r=0; r<4; r++) ps[r] += __shfl_xor(ps[r], msk);
    }
    #pragma unroll
    for (int r=0; r<4; r++) lsum[r] = lsum[r]*scl[r] + ps[r];
    #pragma unroll
    for (int dt=0; dt<8; dt++){
      #pragma unroll
      for (int r=0; r<4; r++) oacc[dt][r] *= scl[r];
    }

    // ---- PV in two k-halves through the per-wave P buffer
    #pragma unroll
    for (int h2=0; h2<2; h2++){
      #pragma unroll
      for (int c4=0; c4<4; c4++){
        #pragma unroll
        for (int r=0; r<4; r++)
          Pw[(g*4+r)*72 + c4*16 + li] = f2bf(sv[h2*4+c4][r]);
      }
      #pragma unroll
      for (int ks2=0; ks2<2; ks2++){
        bf16x8 afr = *(const bf16x8*)&Pw[li*72 + ks2*32 + g*8];
        #pragma unroll
        for (int dt=0; dt<8; dt++){
          const int row = dt*16 + li;
          const int c8g = h2*8 + ks2*4 + g;
          const int chunk = row*16 + (c8g ^ (row&7));
          bf16x8 bfr = *(const bf16x8*)&VL[chunk*8];
          oacc[dt] = MFMA(afr, bfr, oacc[dt]);
        }
      }
    }

    if (pre) WRT(cur^1);
    __syncthreads();
    cur ^= 1;
  } // kt

  // ---- epilogue: fp32 out
  float* Ob = out + qbase*HD;
  #pragma unroll
  for (int dt=0; dt<8; dt++){
    #pragma unroll
    for (int r=0; r<4; r++){
      Ob[(size_t)(w*16 + g*4 + r)*HD + dt*16 + li] = oacc[dt][r] / lsum[r];
    }
  }
  #undef LOADT
  #undef WRT
}

// ---------------- launch -----------------------------------------------------
// d_in = [q, k, v, Wq, bq, Wk, bk, Wv, bv, mask] (confirmed R15).
// ws: Qh | Kimg(32KB x 256) | Vimg | Wbf16 (25.3 MB).
extern "C" void kernel_launch(void* const* d_in, const int* in_sizes, int n_in,
                              void* d_out, int out_size, void* d_ws, size_t ws_size,
                              hipStream_t stream)
{
  short* ws = (short*)d_ws;
  short* wb = ws + 3*PLANE;

  wconv_kernel<<<24, 256, 0, stream>>>(
      (const float*)d_in[3], (const float*)d_in[5], (const float*)d_in[7], wb);

  dim3 pg(BATCH*SEQ/TB, 3);
  proj_kernel<<<pg, 256, 0, stream>>>(
      (const float*)d_in[0], (const float*)d_in[1], (const float*)d_in[2],
      (const float*)d_in[4], (const float*)d_in[6], (const float*)d_in[8],
      wb, ws);

  attn_kernel<<<dim3(BATCH*NTB), 512, 0, stream>>>(ws, (float*)d_out);
}

// Round 21
// 106.501 us; speedup vs baseline: 2.3052x; 1.0762x over previous
//
#include <hip/hip_runtime.h>
#include <hip/hip_bf16.h>

#define BATCH 16
#define SEQ   2048
#define HD    128
#define TB    64            // proj tile rows
#define QB2   128           // attn q-tile rows
#define KB2   128           // attn kv-tile rows
#define NTB   (SEQ/KB2)     // 16 kv tiles per batch
#define PLANE ((size_t)BATCH*SEQ*HD)   // shorts per ws plane

typedef __attribute__((ext_vector_type(8))) short bf16x8;
typedef __attribute__((ext_vector_type(4))) float f32x4;
typedef __attribute__((ext_vector_type(2))) unsigned int u32x2;

#define MFMA(a,b,c) __builtin_amdgcn_mfma_f32_16x16x32_bf16(a,b,c,0,0,0)

__device__ __forceinline__ short f2bf(float f){
  union{float f; unsigned u;} v; v.f = f;
  unsigned r = (v.u + 0x7FFFu + ((v.u>>16)&1u))>>16;
  return (short)r;
}
__device__ __forceinline__ unsigned packbf(float lo, float hi){
  return ((unsigned)(unsigned short)f2bf(hi) << 16) | (unsigned short)f2bf(lo);
}
__device__ __forceinline__ bf16x8 pack8(f32x4 a, f32x4 b){
  bf16x8 r;
  r[0]=f2bf(a[0]); r[1]=f2bf(a[1]); r[2]=f2bf(a[2]); r[3]=f2bf(a[3]);
  r[4]=f2bf(b[0]); r[5]=f2bf(b[1]); r[6]=f2bf(b[2]); r[7]=f2bf(b[3]);
  return r;
}
__device__ __forceinline__ bf16x8 ldfrag(const float* base, size_t eo){
  const float* p = base + eo;
  return pack8(*(const f32x4*)p, *(const f32x4*)(p+4));
}

// ---------------- kernel 0: W fp32 -> bf16 once ------------------------------
__global__ __launch_bounds__(256)
void wconv_kernel(const float* __restrict__ Wq, const float* __restrict__ Wk,
                  const float* __restrict__ Wv, short* __restrict__ wb)
{
  int i = (blockIdx.x*256 + threadIdx.x)*8;
  const float* src = (i < 16384) ? Wq : (i < 32768 ? Wk : Wv);
  int off = i & 16383;
  f32x4 a = *(const f32x4*)(src + off);
  f32x4 b = *(const f32x4*)(src + off + 4);
  *(bf16x8*)(wb + i) = pack8(a, b);
}

// ---------------- kernel 1: projections -> ws (bf16) -------------------------
// z=0: Qh row-major. z=1: Kh 32KB images [128 rows]: chunk(r,c8)=r*16+(c8^(r&7)).
// z=2: Vh^T 32KB images [d][c8g 0..15]: chunk(d,c8g)=d*16+(c8g^(d&7)).
__global__ __launch_bounds__(256)
void proj_kernel(const float* __restrict__ q, const float* __restrict__ k,
                 const float* __restrict__ v,
                 const float* __restrict__ bq, const float* __restrict__ bk,
                 const float* __restrict__ bv,
                 const short* __restrict__ wb, short* __restrict__ ws)
{
  __shared__ __align__(16) short T[TB*136];    // [s_local][h] bounce (z<2)
  __shared__ __align__(16) short VT[HD*72];    // [h][s_local] bounce (z==2)

  const int z = blockIdx.y;
  const float* x  = z==0 ? q  : (z==1 ? k  : v);
  const float* bb = z==0 ? bq : (z==1 ? bk : bv);
  const short* W  = wb + (size_t)z*HD*HD;

  const int tid = threadIdx.x;
  const int w = tid>>6, l = tid&63, li = l&15, g = l>>4;
  const int bx = blockIdx.x;                   // 64-row tile id (b = bx>>5)
  const int rowbase = bx*TB + w*16;

  bf16x8 afr[4];
  const float* xr = x + (size_t)(rowbase+li)*HD + g*8;
  #pragma unroll
  for (int ks=0; ks<4; ks++) afr[ks] = ldfrag(xr, (size_t)ks*32);

  f32x4 acc[8];
  #pragma unroll
  for (int ct=0; ct<8; ct++) acc[ct] = (f32x4){0.f,0.f,0.f,0.f};
  #pragma unroll
  for (int ct=0; ct<8; ct++){
    #pragma unroll
    for (int ks=0; ks<4; ks++){
      bf16x8 bfr = *(const bf16x8*)(W + (size_t)(ct*16+li)*HD + ks*32 + g*8);
      acc[ct] = MFMA(afr[ks], bfr, acc[ct]);
    }
  }

  const int img  = (bx>>1);                    // 128-row image id
  const int half = bx & 1;                     // which 64-row half

  if (z < 2){
    #pragma unroll
    for (int ct=0; ct<8; ct++){
      float bias = bb[ct*16+li];
      #pragma unroll
      for (int r=0; r<4; r++)
        T[(w*16+g*4+r)*136 + ct*16+li] = f2bf(acc[ct][r] + bias);
    }
    __syncthreads();
    if (z == 0){
      short* dst = ws + (size_t)bx*TB*HD;
      #pragma unroll
      for (int it=0; it<4; it++){
        int c = tid + it*256, row = c>>4, c8 = c&15;
        *(bf16x8*)(dst + row*HD + c8*8) = *(const bf16x8*)&T[row*136 + c8*8];
      }
    } else {
      short* dst = ws + PLANE + (size_t)img*16384;
      #pragma unroll
      for (int it=0; it<4; it++){
        int c = tid + it*256, row = c>>4, c8 = c&15;
        int r128 = half*64 + row;
        int chunk = r128*16 + (c8 ^ (r128&7));
        *(bf16x8*)(dst + chunk*8) = *(const bf16x8*)&T[row*136 + c8*8];
      }
    }
  } else {
    #pragma unroll
    for (int ct=0; ct<8; ct++){
      float bias = bb[ct*16+li];
      #pragma unroll
      for (int r=0; r<4; r++)
        VT[(ct*16+li)*72 + w*16+g*4+r] = f2bf(acc[ct][r] + bias);
    }
    __syncthreads();
    short* dst = ws + 2*PLANE + (size_t)img*16384;
    const int d = tid>>1, hf = tid&1;
    #pragma unroll
    for (int j=0; j<4; j++){
      int c8l = hf*4 + j;
      int c8g = half*8 + c8l;
      int chunk = d*16 + (c8g ^ (d&7));
      *(bf16x8*)(dst + chunk*8) = *(const bf16x8*)&VT[d*72 + c8l*8];
    }
  }
}

// ---------------- kernel 2: causal flash attention ---------------------------
// 8 waves x 128-row q-tile, 128-row kv-tiles, double-buffered, 1 barrier/iter.
// SWAPPED QK^T (MFMA(K,Q)): lane l holds S[q=l&15][k=ct*16+(l>>4)*4+r] ->
// softmax row-reduce is in-lane + 2 shfl_xor (vs 4-step trees), P staging is
// 4x ds_write_b64 per half (vs 16 scalar writes). PV unchanged.
__global__ __launch_bounds__(512, 2)
void attn_kernel(const short* __restrict__ ws, float* __restrict__ out)
{
  __shared__ __align__(16) short KVL[2][32768]; // [buf][K 16384 | V 16384]
  __shared__ __align__(16) short PL[8][16*72];  // per-wave P half, padded

  const int bid  = blockIdx.x;                  // 256 blocks
  const int xcd  = bid & 7, slot = bid >> 3;
  const int b    = xcd*2 + (slot >> 4);
  const int qt   = slot & 15;

  const int tid = threadIdx.x;
  const int w = tid>>6, l = tid&63, li = l&15, g = l>>4;

  const short* Qw    = ws;
  const short* KimgB = ws + PLANE   + (size_t)b*NTB*16384;
  const short* VimgB = ws + 2*PLANE + (size_t)b*NTB*16384;

  const size_t qbase = (size_t)b*SEQ + qt*QB2;
  short* Pw = &PL[w][0];
  const float sc = 0.088388347648318447f;       // 1/sqrt(128)

  bf16x8 qfr[4];
  #pragma unroll
  for (int ks=0; ks<4; ks++)
    qfr[ks] = *(const bf16x8*)&Qw[(qbase + w*16 + li)*HD + ks*32 + g*8];

  f32x4 oacc[8];
  #pragma unroll
  for (int dt=0; dt<8; dt++) oacc[dt] = (f32x4){0.f,0.f,0.f,0.f};
  float mreg = -1e30f, lreg = 0.f;              // for q-row (w*16 + li)

  bf16x8 stg[8];
  #define LOADT(kt_) do{                                                    \
    const short* sK = KimgB + (size_t)(kt_)*16384;                          \
    const short* sV = VimgB + (size_t)(kt_)*16384;                          \
    _Pragma("unroll")                                                       \
    for (int j=0;j<4;j++) stg[j]   = *(const bf16x8*)(sK + (tid + j*512)*8);\
    _Pragma("unroll")                                                       \
    for (int j=0;j<4;j++) stg[4+j] = *(const bf16x8*)(sV + (tid + j*512)*8);\
  }while(0)
  #define WRT(nb_) do{                                                     \
    short* dK = &KVL[nb_][0];                                              \
    short* dV = &KVL[nb_][16384];                                          \
    _Pragma("unroll")                                                      \
    for (int j=0;j<4;j++) *(bf16x8*)(dK + (tid+j*512)*8) = stg[j];         \
    _Pragma("unroll")                                                      \
    for (int j=0;j<4;j++) *(bf16x8*)(dV + (tid+j*512)*8) = stg[4+j];       \
  }while(0)

  LOADT(0); WRT(0); __syncthreads();
  int cur = 0;

  for (int kt=0; kt<=qt; kt++){
    const bool pre = (kt < qt);
    if (pre) LOADT(kt+1);

    const short* KL = &KVL[cur][0];
    const short* VL = &KVL[cur][16384];

    // ---- swapped QK^T : lane holds S[q=li][k = ct*16 + g*4 + r]
    f32x4 st[8];
    #pragma unroll
    for (int ct=0; ct<8; ct++) st[ct] = (f32x4){0.f,0.f,0.f,0.f};
    #pragma unroll
    for (int ct=0; ct<8; ct++){
      const int row = ct*16 + li;               // K row (A-frag)
      #pragma unroll
      for (int ks=0; ks<4; ks++){
        const int chunk = row*16 + ((ks*4 + g) ^ (row&7));
        bf16x8 kfr = *(const bf16x8*)&KL[chunk*8];
        st[ct] = MFMA(kfr, qfr[ks], st[ct]);    // SWAPPED operands
      }
    }

    // ---- lane-local online softmax for q-row (w*16 + li)
    float sv[8][4];
    float pm = -1e30f;
    const bool diag = (kt == qt);
    const int qloc = w*16 + li;
    #pragma unroll
    for (int ct=0; ct<8; ct++){
      #pragma unroll
      for (int r=0; r<4; r++){
        float x = st[ct][r]*sc;
        if (diag && (ct*16 + g*4 + r) > qloc) x = -1e30f;
        sv[ct][r] = x;
        pm = fmaxf(pm, x);
      }
    }
    pm = fmaxf(pm, __shfl_xor(pm, 16));
    pm = fmaxf(pm, __shfl_xor(pm, 32));
    float mn   = fmaxf(mreg, pm);
    float sclq = __expf(mreg - mn);
    mreg = mn;
    float psum = 0.f;
    #pragma unroll
    for (int ct=0; ct<8; ct++){
      #pragma unroll
      for (int r=0; r<4; r++){
        float p = __expf(sv[ct][r] - mn);
        sv[ct][r] = p;
        psum += p;
      }
    }
    psum += __shfl_xor(psum, 16);
    psum += __shfl_xor(psum, 32);
    lreg = lreg*sclq + psum;

    // ---- rescale oacc (rows q = g*4+r: factors live in lanes 0..15)
    float sclo[4];
    #pragma unroll
    for (int r=0; r<4; r++) sclo[r] = __shfl(sclq, g*4 + r);
    #pragma unroll
    for (int dt=0; dt<8; dt++){
      #pragma unroll
      for (int r=0; r<4; r++) oacc[dt][r] *= sclo[r];
    }

    // ---- PV in two k-halves; P write = 4x ds_write_b64 per half
    #pragma unroll
    for (int h2=0; h2<2; h2++){
      #pragma unroll
      for (int c4=0; c4<4; c4++){
        const int ct = h2*4 + c4;
        u32x2 pw;
        pw[0] = packbf(sv[ct][0], sv[ct][1]);
        pw[1] = packbf(sv[ct][2], sv[ct][3]);
        *(u32x2*)&Pw[li*72 + c4*16 + g*4] = pw;   // row q=li, k=c4*16+g*4..+3
      }
      #pragma unroll
      for (int ks2=0; ks2<2; ks2++){
        bf16x8 afr = *(const bf16x8*)&Pw[li*72 + ks2*32 + g*8];
        #pragma unroll
        for (int dt=0; dt<8; dt++){
          const int row = dt*16 + li;
          const int c8g = h2*8 + ks2*4 + g;
          const int chunk = row*16 + (c8g ^ (row&7));
          bf16x8 bfr = *(const bf16x8*)&VL[chunk*8];
          oacc[dt] = MFMA(afr, bfr, oacc[dt]);
        }
      }
    }

    if (pre) WRT(cur^1);
    __syncthreads();
    cur ^= 1;
  } // kt

  // ---- epilogue: fp32 out; lsum for row q=g*4+r from lanes 0..15
  float lso[4];
  #pragma unroll
  for (int r=0; r<4; r++) lso[r] = __shfl(lreg, g*4 + r);
  float* Ob = out + qbase*HD;
  #pragma unroll
  for (int dt=0; dt<8; dt++){
    #pragma unroll
    for (int r=0; r<4; r++){
      Ob[(size_t)(w*16 + g*4 + r)*HD + dt*16 + li] = oacc[dt][r] / lso[r];
    }
  }
  #undef LOADT
  #undef WRT
}

// ---------------- launch -----------------------------------------------------
// d_in = [q, k, v, Wq, bq, Wk, bk, Wv, bv, mask] (confirmed R15).
// ws: Qh | Kimg(32KB x 256) | Vimg | Wbf16 (25.3 MB).
extern "C" void kernel_launch(void* const* d_in, const int* in_sizes, int n_in,
                              void* d_out, int out_size, void* d_ws, size_t ws_size,
                              hipStream_t stream)
{
  short* ws = (short*)d_ws;
  short* wb = ws + 3*PLANE;

  wconv_kernel<<<24, 256, 0, stream>>>(
      (const float*)d_in[3], (const float*)d_in[5], (const float*)d_in[7], wb);

  dim3 pg(BATCH*SEQ/TB, 3);
  proj_kernel<<<pg, 256, 0, stream>>>(
      (const float*)d_in[0], (const float*)d_in[1], (const float*)d_in[2],
      (const float*)d_in[4], (const float*)d_in[6], (const float*)d_in[8],
      wb, ws);

  attn_kernel<<<dim3(BATCH*NTB), 512, 0, stream>>>(ws, (float*)d_out);
}